// Round 18
// baseline (168.422 us; speedup 1.0000x reference)
//
#include <hip/hip_runtime.h>
#include <stdint.h>

#define B_   64
#define N_   4096
#define H_   128
#define S_   7
#define D_   32
#define SCALE_ 0.17677669529663687f   // 32^-0.5
#define EPS_   1e-8f
#define LNEPS_ 1e-5f
#define AUS_ 260                      // au row stride (multiple of 4 for b128 reads)

typedef __bf16 bf16x8 __attribute__((ext_vector_type(8)));
typedef float  floatx4 __attribute__((ext_vector_type(4)));

__device__ __forceinline__ uint32_t cvt2(float a, float b){
  union { __bf16 h[2]; uint32_t u; } r;
  r.h[0] = (__bf16)a; r.h[1] = (__bf16)b;
  return r.u;
}
__device__ __forceinline__ float bfLO(uint32_t u){ union{uint32_t i; float f;} x; x.i = u << 16;         return x.f; }
__device__ __forceinline__ float bfHI(uint32_t u){ union{uint32_t i; float f;} x; x.i = u & 0xffff0000u; return x.f; }
__device__ __forceinline__ void up8(uint4 u, float* o){
  o[0]=bfLO(u.x); o[1]=bfHI(u.x); o[2]=bfLO(u.y); o[3]=bfHI(u.y);
  o[4]=bfLO(u.z); o[5]=bfHI(u.z); o[6]=bfLO(u.w); o[7]=bfHI(u.w);
}
// ordered dot over a 32-float row: float4 loads, scalar accumulation in d-order
__device__ __forceinline__ float dot32(const float* __restrict__ wrow, const float* __restrict__ xrow){
  float a = 0.f;
  #pragma unroll
  for (int q = 0; q < 8; ++q){
    float4 wv = *reinterpret_cast<const float4*>(wrow + q * 4);
    a += xrow[q*4+0] * wv.x; a += xrow[q*4+1] * wv.y;
    a += xrow[q*4+2] * wv.z; a += xrow[q*4+3] * wv.w;
  }
  return a;
}

// ---------------------------------------------------------------- init: W-fragments (g-folded, bf16) + c1/c2 + A0 slot prep
// grid 69: blocks 0-3 frags, block 4 c1/c2, blocks 5-68 per-batch A0 (slots<-sini, q0, zero accums).
__global__ __launch_bounds__(256) void init_w(const float* __restrict__ Wk, const float* __restrict__ Wv,
                                              const float* __restrict__ g,  const float* __restrict__ bta,
                                              uint16_t* __restrict__ fragbuf,
                                              float* __restrict__ c1arr, float* __restrict__ c2arr,
                                              const float* __restrict__ sini,
                                              float* __restrict__ slotsbuf, float* __restrict__ qbuf,
                                              float* __restrict__ updbuf, float* __restrict__ rowsumbuf,
                                              const float* __restrict__ Wq,
                                              const float* __restrict__ lnsg, const float* __restrict__ lnsb){
  int t = threadIdx.x;
  if (blockIdx.x < 4){
    int tid = blockIdx.x * 256 + t;
    int nt = tid >> 8, kc = (tid >> 6) & 3, l = tid & 63;
    int col = (nt & 1) * 16 + (l & 15);
    int dbase = kc * 32 + (l >> 4) * 8;
    const float* wr = (nt < 2 ? Wk : Wv) + col * 128 + dbase;
    const float* gr = g + dbase;
    uint32_t u[4];
    #pragma unroll
    for (int j = 0; j < 4; ++j)
      u[j] = cvt2(wr[2*j] * gr[2*j], wr[2*j+1] * gr[2*j+1]);
    *reinterpret_cast<uint4*>(fragbuf + (size_t)tid * 8) = make_uint4(u[0], u[1], u[2], u[3]);
  } else if (blockIdx.x == 4){
    if (t < 128){
      int which = t >> 5, col = t & 31;                 // 0:c1K 1:c2K 2:c1V 3:c2V
      const float* Wb  = (which & 2) ? Wv : Wk;
      const float* vec = (which & 1) ? bta : g;
      float a = 0.f;
      for (int d = 0; d < 128; ++d) a += vec[d] * Wb[col * 128 + d];
      float* dst = (which & 1) ? c2arr : c1arr;
      dst[(which >> 1) * 32 + col] = a;
    }
  } else {
    int b = blockIdx.x - 5;
    int i = t >> 5, c = t & 31;
    __shared__ float sNew[224], sT[224];
    if (t < 224){
      float s = sini[b * 224 + t];
      slotsbuf[b * 224 + t] = s;
      sNew[t] = s;
      updbuf[b * 224 + t] = 0.f;
    }
    if (t < 7) rowsumbuf[b * S_ + t] = 0.f;
    __syncthreads();
    if (t < 224){                                       // LN_s
      float mu = 0.f, sq = 0.f;
      #pragma unroll
      for (int d = 0; d < 32; ++d){ float v = sNew[i * 32 + d]; mu += v; sq += v * v; }
      mu *= (1.f / 32.f);
      float var = sq * (1.f / 32.f) - mu * mu;
      float rstd = rsqrtf(var + LNEPS_);
      sT[t] = (sNew[t] - mu) * rstd * lnsg[c] + lnsb[c];
    }
    __syncthreads();
    if (t < 224){                                       // q0
      qbuf[b * 224 + t] = dot32(Wq + c * 32, sT + i * 32);
    }
  }
}

// ---------------------------------------------------------------- LN(inputs) -> k,v via MFMA on raw x (LN folded into epilogue)
// 64 rows per block, 256 threads (4 waves). Grid 4096. k/v stored bf16.  [r12 exact]
__global__ __launch_bounds__(256) void ln_kv(const float* __restrict__ x,
                                             const uint16_t* __restrict__ fragbuf,
                                             const float* __restrict__ c1arr, const float* __restrict__ c2arr,
                                             uint16_t* __restrict__ kb, uint16_t* __restrict__ vb){
  __shared__ union {
    uint16_t atile[64 * 136];          // bf16 raw-x tile, row stride 136 (272B)
    float    rep[4352];                // repack area: k[64][34], v at +2176
  } sh;
  __shared__ float2 stats[32 * 65];    // [c][row] padded partial (s, s2)
  __shared__ float2 rowstat[64];       // (rstd, -mu*rstd)
  int t = threadIdx.x;
  int l = t & 63, w = t >> 6;
  size_t rowbase = (size_t)blockIdx.x * 64;

  bf16x8 bfr[4][4];                    // [nt][kc]
  #pragma unroll
  for (int nt = 0; nt < 4; ++nt)
    #pragma unroll
    for (int kc = 0; kc < 4; ++kc)
      bfr[nt][kc] = *reinterpret_cast<const bf16x8*>(fragbuf + (((nt * 4 + kc) * 64 + l) * 8));

  float c1c[4], c2c[4];
  #pragma unroll
  for (int nt = 0; nt < 4; ++nt){
    int colk = (nt & 1) * 16 + (l & 15);
    c1c[nt] = c1arr[(nt >> 1) * 32 + colk];
    c2c[nt] = c2arr[(nt >> 1) * 32 + colk];
  }

  const float4* xp = reinterpret_cast<const float4*>(x + rowbase * H_);
  #pragma unroll
  for (int k = 0; k < 8; ++k){
    float4 v = xp[k * 256 + t];        // coalesced 1KB per wave
    int row = 8 * k + (t >> 5);
    uint32_t lo = cvt2(v.x, v.y);
    uint32_t hi = cvt2(v.z, v.w);
    *reinterpret_cast<uint2*>(&sh.atile[row * 136 + (t & 31) * 4]) = make_uint2(lo, hi);
    float s  = v.x + v.y + v.z + v.w;
    float s2 = v.x*v.x + v.y*v.y + v.z*v.z + v.w*v.w;
    stats[(t & 31) * 65 + row] = make_float2(s, s2);
  }
  __syncthreads();

  {
    int row = t >> 2, q = t & 3;
    float s = 0.f, s2 = 0.f;
    #pragma unroll
    for (int j = 0; j < 8; ++j){
      float2 p = stats[(q * 8 + j) * 65 + row];
      s += p.x; s2 += p.y;
    }
    s  += __shfl_xor(s, 1);  s2 += __shfl_xor(s2, 1);
    s  += __shfl_xor(s, 2);  s2 += __shfl_xor(s2, 2);
    if (q == 0){
      float mean = s * (1.f / 128.f);
      float var  = s2 * (1.f / 128.f) - mean * mean;
      float rstd = rsqrtf(var + LNEPS_);
      rowstat[row] = make_float2(rstd, -mean * rstd);
    }
  }
  __syncthreads();

  floatx4 acc[4] = {{0,0,0,0},{0,0,0,0},{0,0,0,0},{0,0,0,0}};
  #pragma unroll
  for (int kc = 0; kc < 4; ++kc){
    bf16x8 afr = *reinterpret_cast<const bf16x8*>(
        &sh.atile[(w * 16 + (l & 15)) * 136 + kc * 32 + (l >> 4) * 8]);
    #pragma unroll
    for (int nt = 0; nt < 4; ++nt)
      acc[nt] = __builtin_amdgcn_mfma_f32_16x16x32_bf16(afr, bfr[nt][kc], acc[nt], 0, 0, 0);
  }
  __syncthreads();                     // atile dead; rep aliases it

  #pragma unroll
  for (int j = 0; j < 4; ++j){
    int rloc = w * 16 + (l >> 4) * 4 + j;
    float2 ab = rowstat[rloc];
    #pragma unroll
    for (int nt = 0; nt < 4; ++nt){
      int base = (nt < 2) ? 0 : 2176;
      int gc = (nt & 1) * 16 + (l & 15);
      sh.rep[base + rloc * 34 + gc] = fmaf(ab.x, acc[nt][j], fmaf(ab.y, c1c[nt], c2c[nt]));
    }
  }
  __syncthreads();

  uint32_t* kout = reinterpret_cast<uint32_t*>(kb + rowbase * 32);
  uint32_t* vout = reinterpret_cast<uint32_t*>(vb + rowbase * 32);
  #pragma unroll
  for (int it = 0; it < 4; ++it){
    int lin = it * 256 + t;
    int row = lin >> 4, wd = (lin & 15) * 2;
    kout[lin] = cvt2(sh.rep[row * 34 + wd],        sh.rep[row * 34 + wd + 1]);
    vout[lin] = cvt2(sh.rep[2176 + row * 34 + wd], sh.rep[2176 + row * 34 + wd + 1]);
  }
}

// ---------------------------------------------------------------- per-iteration attention accumulation (bf16 k/v)  [r17 exact]
// grid: (8 chunks, 64 batches), 256 threads, 512 j per block in 2 tiles; all 16 global loads issued up front.
#define TILE_BODY(KR, VR, J)  do { \
    float kf[32]; \
    up8(KR[0], kf); up8(KR[1], kf + 8); up8(KR[2], kf + 16); up8(KR[3], kf + 24); \
    float dv[7]; \
    _Pragma("unroll") \
    for (int i = 0; i < 7; ++i){ \
      const float* qr = qb + i * 32; \
      float a = 0.f; \
      _Pragma("unroll") \
      for (int c = 0; c < 32; ++c) a += qr[c] * kf[c]; \
      dv[i] = a * SCALE_; \
    } \
    float mx = dv[0]; \
    _Pragma("unroll") \
    for (int i = 1; i < 7; ++i) mx = fmaxf(mx, dv[i]); \
    float p[7]; float sum = 0.f; \
    _Pragma("unroll") \
    for (int i = 0; i < 7; ++i){ p[i] = __expf(dv[i] - mx); sum += p[i]; } \
    float inv = 1.f / sum; \
    _Pragma("unroll") \
    for (int i = 0; i < 7; ++i){ \
      p[i] = p[i] * inv + EPS_; \
      rs[i] += p[i]; \
      au[i * AUS_ + t] = p[i]; \
    } \
    if (lastIter){ \
      _Pragma("unroll") \
      for (int i = 0; i < 7; ++i) aub[(size_t)(b * S_ + i) * N_ + (J)] = p[i]; \
    } \
    float vf[32]; \
    up8(VR[0], vf); up8(VR[1], vf + 8); up8(VR[2], vf + 16); up8(VR[3], vf + 24); \
    _Pragma("unroll") \
    for (int q4 = 0; q4 < 8; ++q4){ \
      int blk = q4 ^ (t & 7); \
      *reinterpret_cast<float4*>(&vtile[t * 32 + blk * 4]) = \
          make_float4(vf[q4*4], vf[q4*4+1], vf[q4*4+2], vf[q4*4+3]); \
    } \
    __syncthreads(); \
    if (t < 224){ \
      const float* aur = au + pi * AUS_ + prt * 64; \
      _Pragma("unroll 4") \
      for (int jj0 = 0; jj0 < 64; jj0 += 4){ \
        float4 a4 = *reinterpret_cast<const float4*>(&aur[jj0]); \
        int jj = prt * 64 + jj0; \
        _Pragma("unroll") \
        for (int q = 0; q < 4; ++q){ \
          float a = (q == 0) ? a4.x : (q == 1) ? a4.y : (q == 2) ? a4.z : a4.w; \
          int blk = pc4 ^ ((jj + q) & 7); \
          float4 vv = *reinterpret_cast<const float4*>(&vtile[(jj + q) * 32 + blk * 4]); \
          ux += a * vv.x; uy += a * vv.y; uz += a * vv.z; uw += a * vv.w; \
        } \
      } \
    } \
    __syncthreads(); \
  } while (0)

__global__ __launch_bounds__(256) void attn_acc(const uint16_t* __restrict__ kb, const uint16_t* __restrict__ vb,
                                                const float* __restrict__ qbuf,
                                                float* __restrict__ updbuf, float* __restrict__ rowsumbuf,
                                                float* __restrict__ aub, int lastIter){
  __shared__ float au[S_ * AUS_];      // [7][260] (16B-aligned rows for b128 reads)
  __shared__ float vtile[256 * 32];    // [256][32] f32, XOR-swizzled float4 blocks
  int b = blockIdx.y, chunk = blockIdx.x, t = threadIdx.x;

  int rem = t % 56, prt = t / 56;      // valid for t<224
  int pi = rem >> 3, pc4 = rem & 7;

  float rs[7];
  #pragma unroll
  for (int i = 0; i < 7; ++i) rs[i] = 0.f;
  float ux = 0.f, uy = 0.f, uz = 0.f, uw = 0.f;

  const float* qb = qbuf + b * (S_ * D_);           // wave-uniform -> s_load

  int j0 = chunk * 512 + t;
  int j1 = j0 + 256;
  const uint4* kr0 = reinterpret_cast<const uint4*>(kb + ((size_t)b * N_ + j0) * 32);
  const uint4* vr0 = reinterpret_cast<const uint4*>(vb + ((size_t)b * N_ + j0) * 32);
  const uint4* kr1 = reinterpret_cast<const uint4*>(kb + ((size_t)b * N_ + j1) * 32);
  const uint4* vr1 = reinterpret_cast<const uint4*>(vb + ((size_t)b * N_ + j1) * 32);
  uint4 k0r[4], v0r[4], k1r[4], v1r[4];
  #pragma unroll
  for (int p = 0; p < 4; ++p){ k0r[p] = kr0[p]; v0r[p] = vr0[p]; k1r[p] = kr1[p]; v1r[p] = vr1[p]; }

  TILE_BODY(k0r, v0r, j0);
  TILE_BODY(k1r, v1r, j1);

  // block-reduce rowsums (reuse au)
  #pragma unroll
  for (int i = 0; i < 7; ++i) au[i * AUS_ + t] = rs[i];
  __syncthreads();
  for (int off = 128; off >= 1; off >>= 1){
    if (t < off){
      #pragma unroll
      for (int i = 0; i < 7; ++i) au[i * AUS_ + t] += au[i * AUS_ + t + off];
    }
    __syncthreads();
  }
  if (t < 7) atomicAdd(&rowsumbuf[b * S_ + t], au[t * AUS_]);
  if (t < 224){
    float* up = updbuf + (size_t)(b * S_ + pi) * 32 + pc4 * 4;
    atomicAdd(up + 0, ux); atomicAdd(up + 1, uy);
    atomicAdd(up + 2, uz); atomicAdd(up + 3, uw);
  }
}

// ---------------------------------------------------------------- slot finalize (C) + next-iter prep (A); float4 weight loads
__global__ __launch_bounds__(256) void slot_update(
    float* __restrict__ slotsbuf, float* __restrict__ updbuf, float* __restrict__ rowsumbuf,
    float* __restrict__ qbuf,
    const float* __restrict__ Wq,
    const float* __restrict__ lnsg, const float* __restrict__ lnsb,
    const float* __restrict__ gwi, const float* __restrict__ gwh,
    const float* __restrict__ gbi, const float* __restrict__ gbh,
    const float* __restrict__ lnmg, const float* __restrict__ lnmb,
    const float* __restrict__ w1, const float* __restrict__ b1,
    const float* __restrict__ w2, const float* __restrict__ b2)
{
  int b = blockIdx.x, t = threadIdx.x;
  int i = t >> 5, c = t & 31;
  __shared__ float sPrev[224], sU[224], sNew[224], sT[224], hM[896];
  float snew = 0.f;

  if (t < 224){
    sPrev[t] = slotsbuf[b * 224 + t];
    sU[t] = updbuf[b * 224 + t] / rowsumbuf[b * S_ + i];
  }
  __syncthreads();
  if (t < 224){                                         // GRU (float4 weight rows, ordered accumulate)
    float gi[3], gh[3];
    #pragma unroll
    for (int x3 = 0; x3 < 3; ++x3){
      int gg = x3 * 32 + c;
      gi[x3] = gbi[gg] + dot32(gwi + gg * 32, sU + i * 32);
      gh[x3] = gbh[gg] + dot32(gwh + gg * 32, sPrev + i * 32);
    }
    float r = 1.f / (1.f + __expf(-(gi[0] + gh[0])));
    float z = 1.f / (1.f + __expf(-(gi[1] + gh[1])));
    float n = tanhf(gi[2] + r * gh[2]);
    snew = (1.f - z) * n + z * sPrev[t];
    sNew[t] = snew;
  }
  __syncthreads();
  if (t < 224){                                         // LN_m
    float mu = 0.f, sq = 0.f;
    #pragma unroll
    for (int d = 0; d < 32; ++d){ float v = sNew[i * 32 + d]; mu += v; sq += v * v; }
    mu *= (1.f / 32.f);
    float var = sq * (1.f / 32.f) - mu * mu;
    float rstd = rsqrtf(var + LNEPS_);
    sT[t] = (snew - mu) * rstd * lnmg[c] + lnmb[c];
  }
  __syncthreads();
  if (t < 224){                                         // MLP layer 1 (4 cols/thread, float4 rows)
    #pragma unroll
    for (int kk = 0; kk < 4; ++kk){
      int hc = c + kk * 32;
      float a = b1[hc] + dot32(w1 + hc * 32, sT + i * 32);
      hM[i * 128 + hc] = fmaxf(a, 0.f);
    }
  }
  __syncthreads();
  if (t < 224){                                         // MLP layer 2 + residual (4 indep accumulators, float4 rows)
    float a0 = 0.f, a1 = 0.f, a2 = 0.f, a3 = 0.f;
    const float* hrow = hM + i * 128;
    const float* wrow = w2 + c * 128;
    for (int hh = 0; hh < 128; hh += 4){
      float4 wv = *reinterpret_cast<const float4*>(wrow + hh);
      a0 += hrow[hh    ] * wv.x;
      a1 += hrow[hh + 1] * wv.y;
      a2 += hrow[hh + 2] * wv.z;
      a3 += hrow[hh + 3] * wv.w;
    }
    snew = snew + b2[c] + ((a0 + a1) + (a2 + a3));
    slotsbuf[b * 224 + t] = snew;
    sNew[t] = snew;
  }

  __syncthreads();
  if (t < 224){                                         // LN_s
    float mu = 0.f, sq = 0.f;
    #pragma unroll
    for (int d = 0; d < 32; ++d){ float v = sNew[i * 32 + d]; mu += v; sq += v * v; }
    mu *= (1.f / 32.f);
    float var = sq * (1.f / 32.f) - mu * mu;
    float rstd = rsqrtf(var + LNEPS_);
    sT[t] = (sNew[t] - mu) * rstd * lnsg[c] + lnsb[c];
  }
  __syncthreads();
  if (t < 224){                                         // q = s_ln @ Wq^T ; zero accumulators
    qbuf[b * 224 + t] = dot32(Wq + c * 32, sT + i * 32);
    updbuf[b * 224 + t] = 0.f;
  }
  if (t < 7) rowsumbuf[b * S_ + t] = 0.f;
}

// ---------------------------------------------------------------- finalize: blocks 0-63 final slot update -> out0/out2; blocks 64-511 normalize -> out1
__global__ __launch_bounds__(256) void finalize(
    const float* __restrict__ slotsbuf, const float* __restrict__ updbuf,
    const float* __restrict__ rowsumbuf, const float* __restrict__ aubuf,
    const float* __restrict__ gwi, const float* __restrict__ gwh,
    const float* __restrict__ gbi, const float* __restrict__ gbh,
    const float* __restrict__ lnmg, const float* __restrict__ lnmb,
    const float* __restrict__ w1, const float* __restrict__ b1,
    const float* __restrict__ w2, const float* __restrict__ b2,
    float* __restrict__ out0, float* __restrict__ out1, float* __restrict__ out2)
{
  int t = threadIdx.x;
  if (blockIdx.x >= 64){
    int blk = blockIdx.x - 64;                          // 0..447
    #pragma unroll
    for (int k2 = 0; k2 < 4; ++k2){
      int idx4 = blk * 1024 + k2 * 256 + t;             // < 458752
      int bi = idx4 >> 10;                              // (b*7+i)
      float inv = 1.f / rowsumbuf[bi];
      float4 a = reinterpret_cast<const float4*>(aubuf)[idx4];
      reinterpret_cast<float4*>(out1)[idx4] = make_float4(a.x*inv, a.y*inv, a.z*inv, a.w*inv);
    }
    return;
  }
  int b = blockIdx.x;
  int i7 = t >> 5, c = t & 31;
  __shared__ float sPrev[224], sU[224], sNew[224], sT[224], hM[896];
  float snew = 0.f;
  if (t < 224){
    sPrev[t] = slotsbuf[b * 224 + t];
    sU[t] = updbuf[b * 224 + t] / rowsumbuf[b * S_ + i7];
  }
  __syncthreads();
  if (t < 224){                                         // GRU (float4 weight rows)
    float gi[3], gh[3];
    #pragma unroll
    for (int x3 = 0; x3 < 3; ++x3){
      int gg = x3 * 32 + c;
      gi[x3] = gbi[gg] + dot32(gwi + gg * 32, sU + i7 * 32);
      gh[x3] = gbh[gg] + dot32(gwh + gg * 32, sPrev + i7 * 32);
    }
    float r = 1.f / (1.f + __expf(-(gi[0] + gh[0])));
    float z = 1.f / (1.f + __expf(-(gi[1] + gh[1])));
    float n = tanhf(gi[2] + r * gh[2]);
    snew = (1.f - z) * n + z * sPrev[t];
    sNew[t] = snew;
  }
  __syncthreads();
  if (t < 224){                                         // LN_m
    float mu = 0.f, sq = 0.f;
    #pragma unroll
    for (int d = 0; d < 32; ++d){ float v = sNew[i7 * 32 + d]; mu += v; sq += v * v; }
    mu *= (1.f / 32.f);
    float var = sq * (1.f / 32.f) - mu * mu;
    float rstd = rsqrtf(var + LNEPS_);
    sT[t] = (snew - mu) * rstd * lnmg[c] + lnmb[c];
  }
  __syncthreads();
  if (t < 224){                                         // MLP layer 1 (float4 rows)
    #pragma unroll
    for (int kk = 0; kk < 4; ++kk){
      int hc = c + kk * 32;
      float a = b1[hc] + dot32(w1 + hc * 32, sT + i7 * 32);
      hM[i7 * 128 + hc] = fmaxf(a, 0.f);
    }
  }
  __syncthreads();
  if (t < 224){                                         // MLP layer 2 + residual -> final slots (float4 rows)
    float a0 = 0.f, a1 = 0.f, a2 = 0.f, a3 = 0.f;
    const float* hrow = hM + i7 * 128;
    const float* wrow = w2 + c * 128;
    for (int hh = 0; hh < 128; hh += 4){
      float4 wv = *reinterpret_cast<const float4*>(wrow + hh);
      a0 += hrow[hh    ] * wv.x;
      a1 += hrow[hh + 1] * wv.y;
      a2 += hrow[hh + 2] * wv.z;
      a3 += hrow[hh + 3] * wv.w;
    }
    snew = snew + b2[c] + ((a0 + a1) + (a2 + a3));
    out0[b * 224 + t] = snew;
    out2[b * 224 + t] = snew;
  }
}

// ----------------------------------------------------------------
extern "C" void kernel_launch(void* const* d_in, const int* in_sizes, int n_in,
                              void* d_out, int out_size, void* d_ws, size_t ws_size,
                              hipStream_t stream)
{
  (void)in_sizes; (void)n_in; (void)out_size; (void)ws_size;
  const float* inp   = (const float*)d_in[0];
  const float* sini  = (const float*)d_in[1];
  const float* lng   = (const float*)d_in[2];
  const float* lnb   = (const float*)d_in[3];
  const float* Wk    = (const float*)d_in[4];
  const float* Wv    = (const float*)d_in[5];
  const float* Wq    = (const float*)d_in[6];
  const float* lnsg  = (const float*)d_in[7];
  const float* lnsb  = (const float*)d_in[8];
  const float* gwi   = (const float*)d_in[9];
  const float* gwh   = (const float*)d_in[10];
  const float* gbi   = (const float*)d_in[11];
  const float* gbh   = (const float*)d_in[12];
  const float* lnmg  = (const float*)d_in[13];
  const float* lnmb  = (const float*)d_in[14];
  const float* w1    = (const float*)d_in[15];
  const float* b1    = (const float*)d_in[16];
  const float* w2    = (const float*)d_in[17];
  const float* b2    = (const float*)d_in[18];

  char* w = (char*)d_ws;
  uint16_t* kbuf   = (uint16_t*)w; w += (size_t)B_ * N_ * 32 * 2;
  uint16_t* vbuf   = (uint16_t*)w; w += (size_t)B_ * N_ * 32 * 2;
  float* qbuf      = (float*)w; w += B_ * 224 * 4;
  float* slotsbuf  = (float*)w; w += B_ * 224 * 4;
  float* updbuf    = (float*)w; w += B_ * 224 * 4;
  float* rowsumbuf = (float*)w; w += B_ * S_ * 4;
  float* aubuf     = (float*)w; w += (size_t)B_ * S_ * N_ * 4;
  uint16_t* fragbuf= (uint16_t*)w; w += 8192 * 2;
  float* c1arr     = (float*)w; w += 64 * 4;
  float* c2arr     = (float*)w; w += 64 * 4;

  float* out0 = (float*)d_out;
  float* out1 = out0 + B_ * S_ * D_;
  float* out2 = out1 + B_ * S_ * N_;

  hipLaunchKernelGGL(init_w, dim3(69), dim3(256), 0, stream,
                     Wk, Wv, lng, lnb, fragbuf, c1arr, c2arr,
                     sini, slotsbuf, qbuf, updbuf, rowsumbuf, Wq, lnsg, lnsb);
  hipLaunchKernelGGL(ln_kv, dim3(4096), dim3(256), 0, stream, inp, fragbuf, c1arr, c2arr, kbuf, vbuf);

  for (int m = 0; m < 4; ++m){
    hipLaunchKernelGGL(attn_acc, dim3(8, 64), dim3(256), 0, stream,
                       kbuf, vbuf, qbuf, updbuf, rowsumbuf, aubuf, (m == 3) ? 1 : 0);
    if (m < 3){
      hipLaunchKernelGGL(slot_update, dim3(64), dim3(256), 0, stream,
                         slotsbuf, updbuf, rowsumbuf, qbuf, Wq, lnsg, lnsb,
                         gwi, gwh, gbi, gbh, lnmg, lnmb, w1, b1, w2, b2);
    }
  }

  hipLaunchKernelGGL(finalize, dim3(512), dim3(256), 0, stream,
                     slotsbuf, updbuf, rowsumbuf, aubuf,
                     gwi, gwh, gbi, gbh, lnmg, lnmb, w1, b1, w2, b2,
                     out0, out1, out2);
}

// Round 19
// 156.825 us; speedup vs baseline: 1.0739x; 1.0739x over previous
//
#include <hip/hip_runtime.h>
#include <stdint.h>

#define B_   64
#define N_   4096
#define H_   128
#define S_   7
#define D_   32
#define NCH8_ 8
#define SCALE_ 0.17677669529663687f   // 32^-0.5
#define EPS_   1e-8f
#define LNEPS_ 1e-5f
#define AUS_ 260                      // au row stride (multiple of 4 for b128 reads)
#define RS_STR_ 448                   // rowsum stride per chunk (64*7)

typedef __bf16 bf16x8 __attribute__((ext_vector_type(8)));
typedef float  floatx4 __attribute__((ext_vector_type(4)));

__device__ __forceinline__ uint32_t cvt2(float a, float b){
  union { __bf16 h[2]; uint32_t u; } r;
  r.h[0] = (__bf16)a; r.h[1] = (__bf16)b;
  return r.u;
}
__device__ __forceinline__ float bfLO(uint32_t u){ union{uint32_t i; float f;} x; x.i = u << 16;         return x.f; }
__device__ __forceinline__ float bfHI(uint32_t u){ union{uint32_t i; float f;} x; x.i = u & 0xffff0000u; return x.f; }
__device__ __forceinline__ void up8(uint4 u, float* o){
  o[0]=bfLO(u.x); o[1]=bfHI(u.x); o[2]=bfLO(u.y); o[3]=bfHI(u.y);
  o[4]=bfLO(u.z); o[5]=bfHI(u.z); o[6]=bfLO(u.w); o[7]=bfHI(u.w);
}
// ordered dot over a 32-float row: float4 loads, scalar accumulation in d-order
__device__ __forceinline__ float dot32(const float* __restrict__ wrow, const float* __restrict__ xrow){
  float a = 0.f;
  #pragma unroll
  for (int q = 0; q < 8; ++q){
    float4 wv = *reinterpret_cast<const float4*>(wrow + q * 4);
    a += xrow[q*4+0] * wv.x; a += xrow[q*4+1] * wv.y;
    a += xrow[q*4+2] * wv.z; a += xrow[q*4+3] * wv.w;
  }
  return a;
}

// ---------------------------------------------------------------- init: W-fragments (g-folded, bf16) + c1/c2 + A0 slot prep
// grid 69: blocks 0-3 frags, block 4 c1/c2, blocks 5-68 per-batch A0 (slots<-sini, q0).
__global__ __launch_bounds__(256) void init_w(const float* __restrict__ Wk, const float* __restrict__ Wv,
                                              const float* __restrict__ g,  const float* __restrict__ bta,
                                              uint16_t* __restrict__ fragbuf,
                                              float* __restrict__ c1arr, float* __restrict__ c2arr,
                                              const float* __restrict__ sini,
                                              float* __restrict__ slotsbuf, float* __restrict__ qbuf,
                                              const float* __restrict__ Wq,
                                              const float* __restrict__ lnsg, const float* __restrict__ lnsb){
  int t = threadIdx.x;
  if (blockIdx.x < 4){
    int tid = blockIdx.x * 256 + t;
    int nt = tid >> 8, kc = (tid >> 6) & 3, l = tid & 63;
    int col = (nt & 1) * 16 + (l & 15);
    int dbase = kc * 32 + (l >> 4) * 8;
    const float* wr = (nt < 2 ? Wk : Wv) + col * 128 + dbase;
    const float* gr = g + dbase;
    uint32_t u[4];
    #pragma unroll
    for (int j = 0; j < 4; ++j)
      u[j] = cvt2(wr[2*j] * gr[2*j], wr[2*j+1] * gr[2*j+1]);
    *reinterpret_cast<uint4*>(fragbuf + (size_t)tid * 8) = make_uint4(u[0], u[1], u[2], u[3]);
  } else if (blockIdx.x == 4){
    if (t < 128){
      int which = t >> 5, col = t & 31;                 // 0:c1K 1:c2K 2:c1V 3:c2V
      const float* Wb  = (which & 2) ? Wv : Wk;
      const float* vec = (which & 1) ? bta : g;
      float a = 0.f;
      for (int d = 0; d < 128; ++d) a += vec[d] * Wb[col * 128 + d];
      float* dst = (which & 1) ? c2arr : c1arr;
      dst[(which >> 1) * 32 + col] = a;
    }
  } else {
    int b = blockIdx.x - 5;
    int i = t >> 5, c = t & 31;
    __shared__ float sNew[224], sT[224];
    if (t < 224){
      float s = sini[b * 224 + t];
      slotsbuf[b * 224 + t] = s;
      sNew[t] = s;
    }
    __syncthreads();
    if (t < 224){                                       // LN_s
      float mu = 0.f, sq = 0.f;
      #pragma unroll
      for (int d = 0; d < 32; ++d){ float v = sNew[i * 32 + d]; mu += v; sq += v * v; }
      mu *= (1.f / 32.f);
      float var = sq * (1.f / 32.f) - mu * mu;
      float rstd = rsqrtf(var + LNEPS_);
      sT[t] = (sNew[t] - mu) * rstd * lnsg[c] + lnsb[c];
    }
    __syncthreads();
    if (t < 224){                                       // q0
      qbuf[b * 224 + t] = dot32(Wq + c * 32, sT + i * 32);
    }
  }
}

// ---------------------------------------------------------------- LN(inputs) -> k,v via MFMA on raw x (LN folded into epilogue)
// 64 rows per block, 256 threads (4 waves). Grid 4096. k/v stored bf16.  [r12 exact]
__global__ __launch_bounds__(256) void ln_kv(const float* __restrict__ x,
                                             const uint16_t* __restrict__ fragbuf,
                                             const float* __restrict__ c1arr, const float* __restrict__ c2arr,
                                             uint16_t* __restrict__ kb, uint16_t* __restrict__ vb){
  __shared__ union {
    uint16_t atile[64 * 136];          // bf16 raw-x tile, row stride 136 (272B)
    float    rep[4352];                // repack area: k[64][34], v at +2176
  } sh;
  __shared__ float2 stats[32 * 65];    // [c][row] padded partial (s, s2)
  __shared__ float2 rowstat[64];       // (rstd, -mu*rstd)
  int t = threadIdx.x;
  int l = t & 63, w = t >> 6;
  size_t rowbase = (size_t)blockIdx.x * 64;

  bf16x8 bfr[4][4];                    // [nt][kc]
  #pragma unroll
  for (int nt = 0; nt < 4; ++nt)
    #pragma unroll
    for (int kc = 0; kc < 4; ++kc)
      bfr[nt][kc] = *reinterpret_cast<const bf16x8*>(fragbuf + (((nt * 4 + kc) * 64 + l) * 8));

  float c1c[4], c2c[4];
  #pragma unroll
  for (int nt = 0; nt < 4; ++nt){
    int colk = (nt & 1) * 16 + (l & 15);
    c1c[nt] = c1arr[(nt >> 1) * 32 + colk];
    c2c[nt] = c2arr[(nt >> 1) * 32 + colk];
  }

  const float4* xp = reinterpret_cast<const float4*>(x + rowbase * H_);
  #pragma unroll
  for (int k = 0; k < 8; ++k){
    float4 v = xp[k * 256 + t];        // coalesced 1KB per wave
    int row = 8 * k + (t >> 5);
    uint32_t lo = cvt2(v.x, v.y);
    uint32_t hi = cvt2(v.z, v.w);
    *reinterpret_cast<uint2*>(&sh.atile[row * 136 + (t & 31) * 4]) = make_uint2(lo, hi);
    float s  = v.x + v.y + v.z + v.w;
    float s2 = v.x*v.x + v.y*v.y + v.z*v.z + v.w*v.w;
    stats[(t & 31) * 65 + row] = make_float2(s, s2);
  }
  __syncthreads();

  {
    int row = t >> 2, q = t & 3;
    float s = 0.f, s2 = 0.f;
    #pragma unroll
    for (int j = 0; j < 8; ++j){
      float2 p = stats[(q * 8 + j) * 65 + row];
      s += p.x; s2 += p.y;
    }
    s  += __shfl_xor(s, 1);  s2 += __shfl_xor(s2, 1);
    s  += __shfl_xor(s, 2);  s2 += __shfl_xor(s2, 2);
    if (q == 0){
      float mean = s * (1.f / 128.f);
      float var  = s2 * (1.f / 128.f) - mean * mean;
      float rstd = rsqrtf(var + LNEPS_);
      rowstat[row] = make_float2(rstd, -mean * rstd);
    }
  }
  __syncthreads();

  floatx4 acc[4] = {{0,0,0,0},{0,0,0,0},{0,0,0,0},{0,0,0,0}};
  #pragma unroll
  for (int kc = 0; kc < 4; ++kc){
    bf16x8 afr = *reinterpret_cast<const bf16x8*>(
        &sh.atile[(w * 16 + (l & 15)) * 136 + kc * 32 + (l >> 4) * 8]);
    #pragma unroll
    for (int nt = 0; nt < 4; ++nt)
      acc[nt] = __builtin_amdgcn_mfma_f32_16x16x32_bf16(afr, bfr[nt][kc], acc[nt], 0, 0, 0);
  }
  __syncthreads();                     // atile dead; rep aliases it

  #pragma unroll
  for (int j = 0; j < 4; ++j){
    int rloc = w * 16 + (l >> 4) * 4 + j;
    float2 ab = rowstat[rloc];
    #pragma unroll
    for (int nt = 0; nt < 4; ++nt){
      int base = (nt < 2) ? 0 : 2176;
      int gc = (nt & 1) * 16 + (l & 15);
      sh.rep[base + rloc * 34 + gc] = fmaf(ab.x, acc[nt][j], fmaf(ab.y, c1c[nt], c2c[nt]));
    }
  }
  __syncthreads();

  uint32_t* kout = reinterpret_cast<uint32_t*>(kb + rowbase * 32);
  uint32_t* vout = reinterpret_cast<uint32_t*>(vb + rowbase * 32);
  #pragma unroll
  for (int it = 0; it < 4; ++it){
    int lin = it * 256 + t;
    int row = lin >> 4, wd = (lin & 15) * 2;
    kout[lin] = cvt2(sh.rep[row * 34 + wd],        sh.rep[row * 34 + wd + 1]);
    vout[lin] = cvt2(sh.rep[2176 + row * 34 + wd], sh.rep[2176 + row * 34 + wd + 1]);
  }
}

// ---------------------------------------------------------------- per-iteration attention accumulation (bf16 k/v)
// grid: (8 chunks, 64 batches), 256 threads, 512 j per block in 2 tiles; issue-early loads.
// NO atomics: per-chunk upd/rowsum slices, plain stores (intra-block partials combined via LDS).
#define TILE_BODY(KR, VR, J)  do { \
    float kf[32]; \
    up8(KR[0], kf); up8(KR[1], kf + 8); up8(KR[2], kf + 16); up8(KR[3], kf + 24); \
    float dv[7]; \
    _Pragma("unroll") \
    for (int i = 0; i < 7; ++i){ \
      const float* qr = qb + i * 32; \
      float a = 0.f; \
      _Pragma("unroll") \
      for (int c = 0; c < 32; ++c) a += qr[c] * kf[c]; \
      dv[i] = a * SCALE_; \
    } \
    float mx = dv[0]; \
    _Pragma("unroll") \
    for (int i = 1; i < 7; ++i) mx = fmaxf(mx, dv[i]); \
    float p[7]; float sum = 0.f; \
    _Pragma("unroll") \
    for (int i = 0; i < 7; ++i){ p[i] = __expf(dv[i] - mx); sum += p[i]; } \
    float inv = 1.f / sum; \
    _Pragma("unroll") \
    for (int i = 0; i < 7; ++i){ \
      p[i] = p[i] * inv + EPS_; \
      rs[i] += p[i]; \
      au[i * AUS_ + t] = p[i]; \
    } \
    if (lastIter){ \
      _Pragma("unroll") \
      for (int i = 0; i < 7; ++i) aub[(size_t)(b * S_ + i) * N_ + (J)] = p[i]; \
    } \
    float vf[32]; \
    up8(VR[0], vf); up8(VR[1], vf + 8); up8(VR[2], vf + 16); up8(VR[3], vf + 24); \
    _Pragma("unroll") \
    for (int q4 = 0; q4 < 8; ++q4){ \
      int blk = q4 ^ (t & 7); \
      *reinterpret_cast<float4*>(&vtile[t * 32 + blk * 4]) = \
          make_float4(vf[q4*4], vf[q4*4+1], vf[q4*4+2], vf[q4*4+3]); \
    } \
    __syncthreads(); \
    if (t < 224){ \
      const float* aur = au + pi * AUS_ + prt * 64; \
      _Pragma("unroll 4") \
      for (int jj0 = 0; jj0 < 64; jj0 += 4){ \
        float4 a4 = *reinterpret_cast<const float4*>(&aur[jj0]); \
        int jj = prt * 64 + jj0; \
        _Pragma("unroll") \
        for (int q = 0; q < 4; ++q){ \
          float a = (q == 0) ? a4.x : (q == 1) ? a4.y : (q == 2) ? a4.z : a4.w; \
          int blk = pc4 ^ ((jj + q) & 7); \
          float4 vv = *reinterpret_cast<const float4*>(&vtile[(jj + q) * 32 + blk * 4]); \
          ux += a * vv.x; uy += a * vv.y; uz += a * vv.z; uw += a * vv.w; \
        } \
      } \
    } \
    __syncthreads(); \
  } while (0)

__global__ __launch_bounds__(256) void attn_acc(const uint16_t* __restrict__ kb, const uint16_t* __restrict__ vb,
                                                const float* __restrict__ qbuf,
                                                float* __restrict__ updbuf, float* __restrict__ rowsumbuf,
                                                float* __restrict__ aub, int lastIter){
  __shared__ float au[S_ * AUS_];      // [7][260] (16B-aligned rows for b128 reads)
  __shared__ float vtile[256 * 32];    // [256][32] f32, XOR-swizzled float4 blocks
  int b = blockIdx.y, chunk = blockIdx.x, t = threadIdx.x;

  int rem = t % 56, prt = t / 56;      // valid for t<224
  int pi = rem >> 3, pc4 = rem & 7;

  float rs[7];
  #pragma unroll
  for (int i = 0; i < 7; ++i) rs[i] = 0.f;
  float ux = 0.f, uy = 0.f, uz = 0.f, uw = 0.f;

  const float* qb = qbuf + b * (S_ * D_);           // wave-uniform -> s_load

  int j0 = chunk * 512 + t;
  int j1 = j0 + 256;
  const uint4* kr0 = reinterpret_cast<const uint4*>(kb + ((size_t)b * N_ + j0) * 32);
  const uint4* vr0 = reinterpret_cast<const uint4*>(vb + ((size_t)b * N_ + j0) * 32);
  const uint4* kr1 = reinterpret_cast<const uint4*>(kb + ((size_t)b * N_ + j1) * 32);
  const uint4* vr1 = reinterpret_cast<const uint4*>(vb + ((size_t)b * N_ + j1) * 32);
  uint4 k0r[4], v0r[4], k1r[4], v1r[4];
  #pragma unroll
  for (int p = 0; p < 4; ++p){ k0r[p] = kr0[p]; v0r[p] = vr0[p]; k1r[p] = kr1[p]; v1r[p] = vr1[p]; }

  TILE_BODY(k0r, v0r, j0);
  TILE_BODY(k1r, v1r, j1);

  // ---- per-thread upd partials -> LDS (vtile is dead); rowsum partials -> au
  if (t < 224)
    *reinterpret_cast<float4*>(&vtile[t * 4]) = make_float4(ux, uy, uz, uw);
  #pragma unroll
  for (int i = 0; i < 7; ++i) au[i * AUS_ + t] = rs[i];
  __syncthreads();

  // ---- rowsum tree-reduce (au)
  for (int off = 128; off >= 1; off >>= 1){
    if (t < off){
      #pragma unroll
      for (int i = 0; i < 7; ++i) au[i * AUS_ + t] += au[i * AUS_ + t + off];
    }
    __syncthreads();
  }
  if (t < 7) rowsumbuf[chunk * RS_STR_ + b * S_ + t] = au[t * AUS_];   // plain store

  // ---- combine 4 prt-partials, plain float4 store to per-chunk slice
  if (t < 56){
    float4 p0 = *reinterpret_cast<const float4*>(&vtile[t * 4]);
    float4 p1 = *reinterpret_cast<const float4*>(&vtile[(t + 56) * 4]);
    float4 p2 = *reinterpret_cast<const float4*>(&vtile[(t + 112) * 4]);
    float4 p3 = *reinterpret_cast<const float4*>(&vtile[(t + 168) * 4]);
    float4 s = make_float4((p0.x + p1.x) + (p2.x + p3.x),
                           (p0.y + p1.y) + (p2.y + p3.y),
                           (p0.z + p1.z) + (p2.z + p3.z),
                           (p0.w + p1.w) + (p2.w + p3.w));
    *reinterpret_cast<float4*>(&updbuf[((size_t)chunk * 64 + b) * 224 + t * 4]) = s;
  }
}

// ---------------------------------------------------------------- slot finalize (C) + next-iter prep (A); sums 8 chunk slices
__global__ __launch_bounds__(256) void slot_update(
    float* __restrict__ slotsbuf, const float* __restrict__ updbuf, const float* __restrict__ rowsumbuf,
    float* __restrict__ qbuf,
    const float* __restrict__ Wq,
    const float* __restrict__ lnsg, const float* __restrict__ lnsb,
    const float* __restrict__ gwi, const float* __restrict__ gwh,
    const float* __restrict__ gbi, const float* __restrict__ gbh,
    const float* __restrict__ lnmg, const float* __restrict__ lnmb,
    const float* __restrict__ w1, const float* __restrict__ b1,
    const float* __restrict__ w2, const float* __restrict__ b2)
{
  int b = blockIdx.x, t = threadIdx.x;
  int i = t >> 5, c = t & 31;
  __shared__ float sPrev[224], sU[224], sNew[224], sT[224], hM[896];
  float snew = 0.f;

  if (t < 224){
    sPrev[t] = slotsbuf[b * 224 + t];
    float u = 0.f, r = 0.f;
    #pragma unroll
    for (int ch = 0; ch < NCH8_; ++ch) u += updbuf[((size_t)ch * 64 + b) * 224 + t];
    #pragma unroll
    for (int ch = 0; ch < NCH8_; ++ch) r += rowsumbuf[ch * RS_STR_ + b * S_ + i];
    sU[t] = u / r;
  }
  __syncthreads();
  if (t < 224){                                         // GRU (float4 weight rows, ordered accumulate)
    float gi[3], gh[3];
    #pragma unroll
    for (int x3 = 0; x3 < 3; ++x3){
      int gg = x3 * 32 + c;
      gi[x3] = gbi[gg] + dot32(gwi + gg * 32, sU + i * 32);
      gh[x3] = gbh[gg] + dot32(gwh + gg * 32, sPrev + i * 32);
    }
    float r = 1.f / (1.f + __expf(-(gi[0] + gh[0])));
    float z = 1.f / (1.f + __expf(-(gi[1] + gh[1])));
    float n = tanhf(gi[2] + r * gh[2]);
    snew = (1.f - z) * n + z * sPrev[t];
    sNew[t] = snew;
  }
  __syncthreads();
  if (t < 224){                                         // LN_m
    float mu = 0.f, sq = 0.f;
    #pragma unroll
    for (int d = 0; d < 32; ++d){ float v = sNew[i * 32 + d]; mu += v; sq += v * v; }
    mu *= (1.f / 32.f);
    float var = sq * (1.f / 32.f) - mu * mu;
    float rstd = rsqrtf(var + LNEPS_);
    sT[t] = (snew - mu) * rstd * lnmg[c] + lnmb[c];
  }
  __syncthreads();
  if (t < 224){                                         // MLP layer 1 (4 cols/thread, float4 rows)
    #pragma unroll
    for (int kk = 0; kk < 4; ++kk){
      int hc = c + kk * 32;
      float a = b1[hc] + dot32(w1 + hc * 32, sT + i * 32);
      hM[i * 128 + hc] = fmaxf(a, 0.f);
    }
  }
  __syncthreads();
  if (t < 224){                                         // MLP layer 2 + residual (4 indep accumulators, float4 rows)
    float a0 = 0.f, a1 = 0.f, a2 = 0.f, a3 = 0.f;
    const float* hrow = hM + i * 128;
    const float* wrow = w2 + c * 128;
    for (int hh = 0; hh < 128; hh += 4){
      float4 wv = *reinterpret_cast<const float4*>(wrow + hh);
      a0 += hrow[hh    ] * wv.x;
      a1 += hrow[hh + 1] * wv.y;
      a2 += hrow[hh + 2] * wv.z;
      a3 += hrow[hh + 3] * wv.w;
    }
    snew = snew + b2[c] + ((a0 + a1) + (a2 + a3));
    slotsbuf[b * 224 + t] = snew;
    sNew[t] = snew;
  }

  __syncthreads();
  if (t < 224){                                         // LN_s
    float mu = 0.f, sq = 0.f;
    #pragma unroll
    for (int d = 0; d < 32; ++d){ float v = sNew[i * 32 + d]; mu += v; sq += v * v; }
    mu *= (1.f / 32.f);
    float var = sq * (1.f / 32.f) - mu * mu;
    float rstd = rsqrtf(var + LNEPS_);
    sT[t] = (sNew[t] - mu) * rstd * lnsg[c] + lnsb[c];
  }
  __syncthreads();
  if (t < 224){                                         // q = s_ln @ Wq^T
    qbuf[b * 224 + t] = dot32(Wq + c * 32, sT + i * 32);
  }
}

// ---------------------------------------------------------------- finalize: blocks 0-63 final slot update -> out0/out2; blocks 64-511 normalize -> out1
__global__ __launch_bounds__(256) void finalize(
    const float* __restrict__ slotsbuf, const float* __restrict__ updbuf,
    const float* __restrict__ rowsumbuf, const float* __restrict__ aubuf,
    const float* __restrict__ gwi, const float* __restrict__ gwh,
    const float* __restrict__ gbi, const float* __restrict__ gbh,
    const float* __restrict__ lnmg, const float* __restrict__ lnmb,
    const float* __restrict__ w1, const float* __restrict__ b1,
    const float* __restrict__ w2, const float* __restrict__ b2,
    float* __restrict__ out0, float* __restrict__ out1, float* __restrict__ out2)
{
  int t = threadIdx.x;
  if (blockIdx.x >= 64){
    int blk = blockIdx.x - 64;                          // 0..447
    #pragma unroll
    for (int k2 = 0; k2 < 4; ++k2){
      int idx4 = blk * 1024 + k2 * 256 + t;             // < 458752
      int bi = idx4 >> 10;                              // (b*7+i)
      float r = 0.f;
      #pragma unroll
      for (int ch = 0; ch < NCH8_; ++ch) r += rowsumbuf[ch * RS_STR_ + bi];
      float inv = 1.f / r;
      float4 a = reinterpret_cast<const float4*>(aubuf)[idx4];
      reinterpret_cast<float4*>(out1)[idx4] = make_float4(a.x*inv, a.y*inv, a.z*inv, a.w*inv);
    }
    return;
  }
  int b = blockIdx.x;
  int i7 = t >> 5, c = t & 31;
  __shared__ float sPrev[224], sU[224], sNew[224], sT[224], hM[896];
  float snew = 0.f;
  if (t < 224){
    sPrev[t] = slotsbuf[b * 224 + t];
    float u = 0.f, r = 0.f;
    #pragma unroll
    for (int ch = 0; ch < NCH8_; ++ch) u += updbuf[((size_t)ch * 64 + b) * 224 + t];
    #pragma unroll
    for (int ch = 0; ch < NCH8_; ++ch) r += rowsumbuf[ch * RS_STR_ + b * S_ + i7];
    sU[t] = u / r;
  }
  __syncthreads();
  if (t < 224){                                         // GRU (float4 weight rows)
    float gi[3], gh[3];
    #pragma unroll
    for (int x3 = 0; x3 < 3; ++x3){
      int gg = x3 * 32 + c;
      gi[x3] = gbi[gg] + dot32(gwi + gg * 32, sU + i7 * 32);
      gh[x3] = gbh[gg] + dot32(gwh + gg * 32, sPrev + i7 * 32);
    }
    float r = 1.f / (1.f + __expf(-(gi[0] + gh[0])));
    float z = 1.f / (1.f + __expf(-(gi[1] + gh[1])));
    float n = tanhf(gi[2] + r * gh[2]);
    snew = (1.f - z) * n + z * sPrev[t];
    sNew[t] = snew;
  }
  __syncthreads();
  if (t < 224){                                         // LN_m
    float mu = 0.f, sq = 0.f;
    #pragma unroll
    for (int d = 0; d < 32; ++d){ float v = sNew[i7 * 32 + d]; mu += v; sq += v * v; }
    mu *= (1.f / 32.f);
    float var = sq * (1.f / 32.f) - mu * mu;
    float rstd = rsqrtf(var + LNEPS_);
    sT[t] = (snew - mu) * rstd * lnmg[c] + lnmb[c];
  }
  __syncthreads();
  if (t < 224){                                         // MLP layer 1 (float4 rows)
    #pragma unroll
    for (int kk = 0; kk < 4; ++kk){
      int hc = c + kk * 32;
      float a = b1[hc] + dot32(w1 + hc * 32, sT + i7 * 32);
      hM[i7 * 128 + hc] = fmaxf(a, 0.f);
    }
  }
  __syncthreads();
  if (t < 224){                                         // MLP layer 2 + residual -> final slots (float4 rows)
    float a0 = 0.f, a1 = 0.f, a2 = 0.f, a3 = 0.f;
    const float* hrow = hM + i7 * 128;
    const float* wrow = w2 + c * 128;
    for (int hh = 0; hh < 128; hh += 4){
      float4 wv = *reinterpret_cast<const float4*>(wrow + hh);
      a0 += hrow[hh    ] * wv.x;
      a1 += hrow[hh + 1] * wv.y;
      a2 += hrow[hh + 2] * wv.z;
      a3 += hrow[hh + 3] * wv.w;
    }
    snew = snew + b2[c] + ((a0 + a1) + (a2 + a3));
    out0[b * 224 + t] = snew;
    out2[b * 224 + t] = snew;
  }
}

// ----------------------------------------------------------------
extern "C" void kernel_launch(void* const* d_in, const int* in_sizes, int n_in,
                              void* d_out, int out_size, void* d_ws, size_t ws_size,
                              hipStream_t stream)
{
  (void)in_sizes; (void)n_in; (void)out_size; (void)ws_size;
  const float* inp   = (const float*)d_in[0];
  const float* sini  = (const float*)d_in[1];
  const float* lng   = (const float*)d_in[2];
  const float* lnb   = (const float*)d_in[3];
  const float* Wk    = (const float*)d_in[4];
  const float* Wv    = (const float*)d_in[5];
  const float* Wq    = (const float*)d_in[6];
  const float* lnsg  = (const float*)d_in[7];
  const float* lnsb  = (const float*)d_in[8];
  const float* gwi   = (const float*)d_in[9];
  const float* gwh   = (const float*)d_in[10];
  const float* gbi   = (const float*)d_in[11];
  const float* gbh   = (const float*)d_in[12];
  const float* lnmg  = (const float*)d_in[13];
  const float* lnmb  = (const float*)d_in[14];
  const float* w1    = (const float*)d_in[15];
  const float* b1    = (const float*)d_in[16];
  const float* w2    = (const float*)d_in[17];
  const float* b2    = (const float*)d_in[18];

  char* w = (char*)d_ws;
  uint16_t* kbuf   = (uint16_t*)w; w += (size_t)B_ * N_ * 32 * 2;
  uint16_t* vbuf   = (uint16_t*)w; w += (size_t)B_ * N_ * 32 * 2;
  float* qbuf      = (float*)w; w += B_ * 224 * 4;
  float* slotsbuf  = (float*)w; w += B_ * 224 * 4;
  float* updbuf    = (float*)w; w += (size_t)NCH8_ * B_ * 224 * 4;   // per-chunk slices
  float* rowsumbuf = (float*)w; w += NCH8_ * RS_STR_ * 4;            // per-chunk slices
  float* aubuf     = (float*)w; w += (size_t)B_ * S_ * N_ * 4;
  uint16_t* fragbuf= (uint16_t*)w; w += 8192 * 2;
  float* c1arr     = (float*)w; w += 64 * 4;
  float* c2arr     = (float*)w; w += 64 * 4;

  float* out0 = (float*)d_out;
  float* out1 = out0 + B_ * S_ * D_;
  float* out2 = out1 + B_ * S_ * N_;

  hipLaunchKernelGGL(init_w, dim3(69), dim3(256), 0, stream,
                     Wk, Wv, lng, lnb, fragbuf, c1arr, c2arr,
                     sini, slotsbuf, qbuf, Wq, lnsg, lnsb);
  hipLaunchKernelGGL(ln_kv, dim3(4096), dim3(256), 0, stream, inp, fragbuf, c1arr, c2arr, kbuf, vbuf);

  for (int m = 0; m < 4; ++m){
    hipLaunchKernelGGL(attn_acc, dim3(NCH8_, 64), dim3(256), 0, stream,
                       kbuf, vbuf, qbuf, updbuf, rowsumbuf, aubuf, (m == 3) ? 1 : 0);
    if (m < 3){
      hipLaunchKernelGGL(slot_update, dim3(64), dim3(256), 0, stream,
                         slotsbuf, updbuf, rowsumbuf, qbuf, Wq, lnsg, lnsb,
                         gwi, gwh, gbi, gbh, lnmg, lnmb, w1, b1, w2, b2);
    }
  }

  hipLaunchKernelGGL(finalize, dim3(512), dim3(256), 0, stream,
                     slotsbuf, updbuf, rowsumbuf, aubuf,
                     gwi, gwh, gbi, gbh, lnmg, lnmb, w1, b1, w2, b2,
                     out0, out1, out2);
}